// Round 5
// baseline (116.226 us; speedup 1.0000x reference)
//
#include <hip/hip_runtime.h>

typedef _Float16 f16x8 __attribute__((ext_vector_type(8)));
typedef unsigned short u16x8 __attribute__((ext_vector_type(8)));
typedef float f32x4 __attribute__((ext_vector_type(4)));

#define NS 1024
#define NQ 1024
#define DD 128
#define NWAY 8
#define SCHUNK 64     // supports per block (4 subtiles of 16)
#define QPER 16       // queries per block
#define NSBLK (NS / SCHUNK)   // 16

// 16-lane (row) sum via DPP row_shr — VALU pipe, no LDS.
// Lane with (lane&15)==15 ends with the sum of its 16-lane row.
__device__ __forceinline__ float rowsum16(float v) {
    int t;
    t = __builtin_amdgcn_update_dpp(0, __float_as_int(v), 0x111, 0xF, 0xF, true);
    v += __int_as_float(t);
    t = __builtin_amdgcn_update_dpp(0, __float_as_int(v), 0x112, 0xF, 0xF, true);
    v += __int_as_float(t);
    t = __builtin_amdgcn_update_dpp(0, __float_as_int(v), 0x114, 0xF, 0xF, true);
    v += __int_as_float(t);
    t = __builtin_amdgcn_update_dpp(0, __float_as_int(v), 0x118, 0xF, 0xF, true);
    v += __int_as_float(t);
    return v;
}

// Main kernel: 64 supports x 16 queries per block.
// Wave split: wave = (jh<<1)|ws; ws picks s-subtile pair {2ws,2ws+1},
// jh picks h-half (h = jh*32 + j2*16 + c). The two jh-waves for the same
// supports merge their partial sims via LDS atomics (b1 folded per-h, so
// no double count). This halves bfrag to 32 VGPRs -> ~116 live regs ->
// 4 waves/SIMD at launch_bounds(256,4), 2x the R4 occupancy.
// b2 dropped (uniform logit shift; log_softmax-invariant).
__global__ __launch_bounds__(256, 4) void siamese_main(
    const float* __restrict__ support_x,
    const int* __restrict__ support_y,
    const float* __restrict__ query_x,
    const float* __restrict__ W1,
    const float* __restrict__ b1,
    const float* __restrict__ W2,
    float* __restrict__ part)   // [NSBLK][NQ][NWAY]
{
    __shared__ _Float16 qtile[QPER][DD];       // 4 KB
    __shared__ float clsbuf[QPER][NWAY];       // 512 B

    const int t = threadIdx.x;
    const int wave = t >> 6;
    const int lane = t & 63;
    const int c = lane & 15;     // MFMA m / n index
    const int quad = lane >> 4;  // MFMA k-group / row-group

    const int ws = wave & 1;     // s-subtile pair
    const int jh = wave >> 1;    // h-half (0: h<32, 1: h>=32)

    const int sblk = blockIdx.x & (NSBLK - 1);
    const int qblk = blockIdx.x >> 4;
    const int s0 = sblk * SCHUNK;
    const int q0 = qblk * QPER;

    // ---- one-time: support A-fragments in registers ----
    // sup[ii][k]: lane (quad,c) holds support row s0+(2*ws+ii)*16+c,
    // d = k*32 + quad*8 + [0,8)   (A[m=lane&15][k=quad*8+e])
    f16x8 sup[2][4];
#pragma unroll
    for (int ii = 0; ii < 2; ++ii) {
        const float* sp = support_x + (size_t)(s0 + (2 * ws + ii) * 16 + c) * DD + quad * 8;
#pragma unroll
        for (int k = 0; k < 4; ++k) {
            float4 v0 = *(const float4*)(sp + k * 32);
            float4 v1 = *(const float4*)(sp + k * 32 + 4);
            f16x8 s;
            s[0] = (_Float16)v0.x; s[1] = (_Float16)v0.y;
            s[2] = (_Float16)v0.z; s[3] = (_Float16)v0.w;
            s[4] = (_Float16)v1.x; s[5] = (_Float16)v1.y;
            s[6] = (_Float16)v1.z; s[7] = (_Float16)v1.w;
            sup[ii][k] = s;
        }
    }

    // ---- one-time: W1 B-fragments for this wave's h-half ----
    f16x8 bfrag[2][4];
    float b1h[2], w2h[2];
#pragma unroll
    for (int j2 = 0; j2 < 2; ++j2) {
        const int h = jh * 32 + j2 * 16 + c;
#pragma unroll
        for (int k = 0; k < 4; ++k) {
            const float* wp = W1 + h * DD + k * 32 + quad * 8;
            float4 v0 = *(const float4*)(wp);
            float4 v1 = *(const float4*)(wp + 4);
            f16x8 s;
            s[0] = (_Float16)v0.x; s[1] = (_Float16)v0.y;
            s[2] = (_Float16)v0.z; s[3] = (_Float16)v0.w;
            s[4] = (_Float16)v1.x; s[5] = (_Float16)v1.y;
            s[6] = (_Float16)v1.z; s[7] = (_Float16)v1.w;
            bfrag[j2][k] = s;
        }
        b1h[j2] = b1[h];
        w2h[j2] = W2[h];
    }

    int lbl[2][4];
#pragma unroll
    for (int ii = 0; ii < 2; ++ii)
#pragma unroll
        for (int r = 0; r < 4; ++r)
            lbl[ii][r] = support_y[s0 + (2 * ws + ii) * 16 + quad * 4 + r];

    // ---- stage QPER query rows (f16) + zero class buckets ----
    {
        const int q = t >> 4;
        const int dd = (t & 15) * 8;
        const float* qp = query_x + (size_t)(q0 + q) * DD + dd;
        float4 v0 = *(const float4*)(qp);
        float4 v1 = *(const float4*)(qp + 4);
        f16x8 s;
        s[0] = (_Float16)v0.x; s[1] = (_Float16)v0.y;
        s[2] = (_Float16)v0.z; s[3] = (_Float16)v0.w;
        s[4] = (_Float16)v1.x; s[5] = (_Float16)v1.y;
        s[6] = (_Float16)v1.z; s[7] = (_Float16)v1.w;
        *(f16x8*)&qtile[q][dd] = s;
    }
    if (t < QPER * NWAY) clsbuf[t >> 3][t & 7] = 0.f;
    __syncthreads();

    for (int qq = 0; qq < QPER; ++qq) {
        // accumulators pre-seeded with b1 (C col = c -> h = jh*32+j2*16+c)
        f32x4 acc[2][2];
#pragma unroll
        for (int ii = 0; ii < 2; ++ii)
#pragma unroll
            for (int j2 = 0; j2 < 2; ++j2)
                acc[ii][j2] = (f32x4){b1h[j2], b1h[j2], b1h[j2], b1h[j2]};

#pragma unroll
        for (int k = 0; k < 4; ++k) {
            // quad-uniform broadcast read of the query slice for this k
            f16x8 qf = *(const f16x8*)&qtile[qq][k * 32 + quad * 8];
#pragma unroll
            for (int ii = 0; ii < 2; ++ii) {
                f16x8 dv = sup[ii][k] - qf;
                union { f16x8 f; u16x8 u; } cv;
                cv.f = dv;
                cv.u = cv.u & (unsigned short)0x7fffu;  // |diff|
#pragma unroll
                for (int j2 = 0; j2 < 2; ++j2)
                    acc[ii][j2] = __builtin_amdgcn_mfma_f32_16x16x32_f16(
                        cv.f, bfrag[j2][k], acc[ii][j2], 0, 0, 0);
            }
        }

        // epilogue: partial sim over this wave's 32 h; LDS-atomic class bucket
#pragma unroll
        for (int ii = 0; ii < 2; ++ii) {
#pragma unroll
            for (int r = 0; r < 4; ++r) {
                float val = fmaf(fmaxf(acc[ii][0][r], 0.f), w2h[0],
                            fmaxf(acc[ii][1][r], 0.f) * w2h[1]);
                float v = rowsum16(val);
                if (c == 15) atomicAdd(&clsbuf[qq][lbl[ii][r]], v);
            }
        }
    }
    __syncthreads();

    // one coalesced 128-float store: part[sblk][q0..q0+15][0..7]
    if (t < QPER * NWAY)
        part[(size_t)sblk * (NQ * NWAY) + q0 * NWAY + t] = clsbuf[t >> 3][t & 7];
}

// Finalize: sum NSBLK partials, counts, per-class mean, log_softmax.
// Grid 8 x 128 threads (one thread per query).
__global__ void siamese_finalize(
    const int* __restrict__ support_y,
    const float* __restrict__ part,
    float* __restrict__ out)
{
    __shared__ float cnt[NWAY];
    const int t = threadIdx.x;
    if (t < NWAY) cnt[t] = 0.f;
    __syncthreads();
#pragma unroll
    for (int i = 0; i < NS / 128; ++i)
        atomicAdd(&cnt[support_y[t * (NS / 128) + i]], 1.0f);
    __syncthreads();

    const int q = blockIdx.x * 128 + t;
    float lg[NWAY];
    float mx = -1e30f;
#pragma unroll
    for (int k = 0; k < NWAY; ++k) {
        float s = 0.f;
#pragma unroll
        for (int sb = 0; sb < NSBLK; ++sb)
            s += part[(size_t)sb * (NQ * NWAY) + q * NWAY + k];
        lg[k] = s / cnt[k];
        mx = fmaxf(mx, lg[k]);
    }
    float ss = 0.f;
#pragma unroll
    for (int k = 0; k < NWAY; ++k) ss += expf(lg[k] - mx);
    const float lse = mx + logf(ss);
#pragma unroll
    for (int k = 0; k < NWAY; ++k) out[q * NWAY + k] = lg[k] - lse;
}

extern "C" void kernel_launch(void* const* d_in, const int* in_sizes, int n_in,
                              void* d_out, int out_size, void* d_ws, size_t ws_size,
                              hipStream_t stream) {
    const float* support_x = (const float*)d_in[0];
    const int* support_y   = (const int*)d_in[1];
    const float* query_x   = (const float*)d_in[2];
    // d_in[3] = n_way (scalar, fixed at 8) — unused
    const float* W1 = (const float*)d_in[4];
    const float* b1 = (const float*)d_in[5];
    const float* W2 = (const float*)d_in[6];
    // d_in[7] = b2 — dropped (uniform logit shift, log_softmax-invariant)

    float* part = (float*)d_ws;  // [NSBLK][NQ][NWAY] fp32 partials, 512 KB
    // every slot is written unconditionally by siamese_main — no memset needed

    siamese_main<<<dim3(NSBLK * (NQ / QPER)), dim3(256), 0, stream>>>(
        support_x, support_y, query_x, W1, b1, W2, part);
    siamese_finalize<<<dim3(NQ / 128), dim3(128), 0, stream>>>(
        support_y, part, (float*)d_out);
}

// Round 6
// 104.027 us; speedup vs baseline: 1.1173x; 1.1173x over previous
//
#include <hip/hip_runtime.h>

typedef _Float16 f16x8 __attribute__((ext_vector_type(8)));
typedef unsigned short u16x8 __attribute__((ext_vector_type(8)));
typedef float f32x4 __attribute__((ext_vector_type(4)));

#define NS 1024
#define NQ 1024
#define DD 128
#define NWAY 8
#define SCHUNK 128
#define QPER 8

// 16-lane (row) sum via DPP row_shr — VALU pipe, no LDS.
// Lane with (lane&15)==15 ends with the sum of its 16-lane row.
__device__ __forceinline__ float rowsum16(float v) {
    int t;
    t = __builtin_amdgcn_update_dpp(0, __float_as_int(v), 0x111, 0xF, 0xF, true);
    v += __int_as_float(t);
    t = __builtin_amdgcn_update_dpp(0, __float_as_int(v), 0x112, 0xF, 0xF, true);
    v += __int_as_float(t);
    t = __builtin_amdgcn_update_dpp(0, __float_as_int(v), 0x114, 0xF, 0xF, true);
    v += __int_as_float(t);
    t = __builtin_amdgcn_update_dpp(0, __float_as_int(v), 0x118, 0xF, 0xF, true);
    v += __int_as_float(t);
    return v;
}

// Main kernel: 128 supports x 8 queries per block, 2 queries in flight.
// sim(q,s) = relu(|q-s| @ W1^T + b1) @ W2, bucketed by class.
// b2 dropped (uniform logit shift; log_softmax-invariant).
// NOTE launch_bounds: (256,2) is the ONLY clean config. (256,3) [R3] and
// (256,4) [R5] both caused the allocator to spill fragments -> 30-100 MB
// of scratch HBM traffic per dispatch. Occupancy stays ~2 waves/SIMD, so
// latency is hidden with in-wave ILP: dual-query MFMA/VALU streams.
__global__ __launch_bounds__(256, 2) void siamese_main(
    const float* __restrict__ support_x,
    const int* __restrict__ support_y,
    const float* __restrict__ query_x,
    const float* __restrict__ W1,
    const float* __restrict__ b1,
    const float* __restrict__ W2,
    float* __restrict__ part)   // [8 sblk][NQ][NWAY]
{
    __shared__ _Float16 qtile[QPER][DD];       // 2 KB
    __shared__ float clsbuf[QPER][NWAY];       // 256 B

    const int t = threadIdx.x;
    const int wave = t >> 6;
    const int lane = t & 63;
    const int c = lane & 15;     // MFMA m / n index
    const int quad = lane >> 4;  // MFMA k-group / row-group

    const int sblk = blockIdx.x & 7;
    const int qblk = blockIdx.x >> 3;
    const int s0 = sblk * SCHUNK;
    const int q0 = qblk * QPER;

    // ---- one-time: support A-fragments in registers ----
    // sup[ii][k]: lane (quad,c) holds support row (s0 + (2*wave+ii)*16 + c),
    // d = k*32 + quad*8 + [0,8)   (A[m=lane&15][k=quad*8+e])
    f16x8 sup[2][4];
#pragma unroll
    for (int ii = 0; ii < 2; ++ii) {
        const int st = 2 * wave + ii;
        const float* sp = support_x + (size_t)(s0 + st * 16 + c) * DD + quad * 8;
#pragma unroll
        for (int k = 0; k < 4; ++k) {
            float4 v0 = *(const float4*)(sp + k * 32);
            float4 v1 = *(const float4*)(sp + k * 32 + 4);
            f16x8 s;
            s[0] = (_Float16)v0.x; s[1] = (_Float16)v0.y;
            s[2] = (_Float16)v0.z; s[3] = (_Float16)v0.w;
            s[4] = (_Float16)v1.x; s[5] = (_Float16)v1.y;
            s[6] = (_Float16)v1.z; s[7] = (_Float16)v1.w;
            sup[ii][k] = s;
        }
    }

    // ---- one-time: W1 B-fragments, b1/W2 per-lane, labels per-lane ----
    f16x8 bfrag[4][4];
    float b1h[4], w2h[4];
#pragma unroll
    for (int j = 0; j < 4; ++j) {
        const int h = j * 16 + c;
#pragma unroll
        for (int k = 0; k < 4; ++k) {
            const float* wp = W1 + h * DD + k * 32 + quad * 8;
            float4 v0 = *(const float4*)(wp);
            float4 v1 = *(const float4*)(wp + 4);
            f16x8 s;
            s[0] = (_Float16)v0.x; s[1] = (_Float16)v0.y;
            s[2] = (_Float16)v0.z; s[3] = (_Float16)v0.w;
            s[4] = (_Float16)v1.x; s[5] = (_Float16)v1.y;
            s[6] = (_Float16)v1.z; s[7] = (_Float16)v1.w;
            bfrag[j][k] = s;
        }
        b1h[j] = b1[h];
        w2h[j] = W2[h];
    }

    int lbl[2][4];
#pragma unroll
    for (int ii = 0; ii < 2; ++ii)
#pragma unroll
        for (int r = 0; r < 4; ++r)
            lbl[ii][r] = support_y[s0 + (2 * wave + ii) * 16 + quad * 4 + r];

    // ---- stage QPER query rows (f16) + zero class buckets ----
    {
        const int q = t >> 5;
        const int dd = (t & 31) * 4;
        float4 v = *(const float4*)(query_x + (size_t)(q0 + q) * DD + dd);
        _Float16* dst = &qtile[q][dd];
        dst[0] = (_Float16)v.x; dst[1] = (_Float16)v.y;
        dst[2] = (_Float16)v.z; dst[3] = (_Float16)v.w;
    }
    if (t < QPER * NWAY) clsbuf[t >> 3][t & 7] = 0.f;
    __syncthreads();

    for (int qq = 0; qq < QPER; qq += 2) {
        // accumulators pre-seeded with b1 (C col = c -> h = j*16+c)
        f32x4 acc[2][2][4];   // [q-pair][ii][j]
#pragma unroll
        for (int p = 0; p < 2; ++p)
#pragma unroll
            for (int ii = 0; ii < 2; ++ii)
#pragma unroll
                for (int j = 0; j < 4; ++j)
                    acc[p][ii][j] = (f32x4){b1h[j], b1h[j], b1h[j], b1h[j]};

#pragma unroll
        for (int k = 0; k < 4; ++k) {
            // quad-uniform broadcast reads of both query slices for this k
            f16x8 qf0 = *(const f16x8*)&qtile[qq][k * 32 + quad * 8];
            f16x8 qf1 = *(const f16x8*)&qtile[qq + 1][k * 32 + quad * 8];
#pragma unroll
            for (int ii = 0; ii < 2; ++ii) {
                union { f16x8 f; u16x8 u; } cv0, cv1;
                cv0.f = sup[ii][k] - qf0;
                cv1.f = sup[ii][k] - qf1;
                cv0.u = cv0.u & (unsigned short)0x7fffu;  // |diff|
                cv1.u = cv1.u & (unsigned short)0x7fffu;
#pragma unroll
                for (int j = 0; j < 4; ++j) {
                    acc[0][ii][j] = __builtin_amdgcn_mfma_f32_16x16x32_f16(
                        cv0.f, bfrag[j][k], acc[0][ii][j], 0, 0, 0);
                    acc[1][ii][j] = __builtin_amdgcn_mfma_f32_16x16x32_f16(
                        cv1.f, bfrag[j][k], acc[1][ii][j], 0, 0, 0);
                }
            }
        }

        // epilogue: sim(s) = sum_h relu(H)*W2[h]; LDS-atomic class bucket
#pragma unroll
        for (int p = 0; p < 2; ++p) {
#pragma unroll
            for (int ii = 0; ii < 2; ++ii) {
#pragma unroll
                for (int r = 0; r < 4; ++r) {
                    float val = 0.f;
#pragma unroll
                    for (int j = 0; j < 4; ++j)
                        val = fmaf(fmaxf(acc[p][ii][j][r], 0.f), w2h[j], val);
                    float v = rowsum16(val);
                    if (c == 15) atomicAdd(&clsbuf[qq + p][lbl[ii][r]], v);
                }
            }
        }
    }
    __syncthreads();

    // one coalesced 64-float store: part[sblk][q0..q0+7][0..7]
    if (t < QPER * NWAY)
        part[(size_t)sblk * (NQ * NWAY) + q0 * NWAY + t] = clsbuf[t >> 3][t & 7];
}

// Finalize: sum 8 partials, counts, per-class mean, log_softmax.
// Grid 8 x 128 threads (one thread per query).
__global__ void siamese_finalize(
    const int* __restrict__ support_y,
    const float* __restrict__ part,
    float* __restrict__ out)
{
    __shared__ float cnt[NWAY];
    const int t = threadIdx.x;
    if (t < NWAY) cnt[t] = 0.f;
    __syncthreads();
#pragma unroll
    for (int i = 0; i < NS / 128; ++i)
        atomicAdd(&cnt[support_y[t * (NS / 128) + i]], 1.0f);
    __syncthreads();

    const int q = blockIdx.x * 128 + t;
    float lg[NWAY];
    float mx = -1e30f;
#pragma unroll
    for (int k = 0; k < NWAY; ++k) {
        float s = 0.f;
#pragma unroll
        for (int sb = 0; sb < 8; ++sb)
            s += part[(size_t)sb * (NQ * NWAY) + q * NWAY + k];
        lg[k] = s / cnt[k];
        mx = fmaxf(mx, lg[k]);
    }
    float ss = 0.f;
#pragma unroll
    for (int k = 0; k < NWAY; ++k) ss += expf(lg[k] - mx);
    const float lse = mx + logf(ss);
#pragma unroll
    for (int k = 0; k < NWAY; ++k) out[q * NWAY + k] = lg[k] - lse;
}

extern "C" void kernel_launch(void* const* d_in, const int* in_sizes, int n_in,
                              void* d_out, int out_size, void* d_ws, size_t ws_size,
                              hipStream_t stream) {
    const float* support_x = (const float*)d_in[0];
    const int* support_y   = (const int*)d_in[1];
    const float* query_x   = (const float*)d_in[2];
    // d_in[3] = n_way (scalar, fixed at 8) — unused
    const float* W1 = (const float*)d_in[4];
    const float* b1 = (const float*)d_in[5];
    const float* W2 = (const float*)d_in[6];
    // d_in[7] = b2 — dropped (uniform logit shift, log_softmax-invariant)

    float* part = (float*)d_ws;  // [8][NQ][NWAY] fp32 partials, 256 KB
    // every slot is written unconditionally by siamese_main — no memset needed

    siamese_main<<<dim3((NS / SCHUNK) * (NQ / QPER)), dim3(256), 0, stream>>>(
        support_x, support_y, query_x, W1, b1, W2, part);
    siamese_finalize<<<dim3(NQ / 128), dim3(128), 0, stream>>>(
        support_y, part, (float*)d_out);
}